// Round 9
// baseline (705.662 us; speedup 1.0000x reference)
//
#include <hip/hip_runtime.h>
#include <stdint.h>

#define M_DIM 4096
#define K_DIM 4096
#define N_DIM 12288

// fallback tile (old verified 128^2 kernel)
#define BM 128
#define BN 128
#define BK 64

typedef __attribute__((ext_vector_type(8))) _Float16 half8;
typedef __attribute__((ext_vector_type(2))) __fp16 fp16x2;
typedef __attribute__((ext_vector_type(4))) float f32x4;

#define GLOAD_LDS16(gp, lp)                                                   \
  __builtin_amdgcn_global_load_lds(                                           \
      (const __attribute__((address_space(1))) void*)(gp),                    \
      (__attribute__((address_space(3))) void*)(lp), 16, 0, 0)

// 8 nibbles (high-first) -> 8 f16 weights, single-rounded:
// h = 1024 + n exactly (0x6400|n); (h - 1024) is exact; one mul rounds.
static __device__ __forceinline__ half8 dequant8(uint32_t q, _Float16 sh) {
  union { uint32_t u[4]; half8 h; } w;
  w.u[0] = 0x64006400u | ((q >> 28) & 0xFu) | ((q >> 8)  & 0xF0000u);
  w.u[1] = 0x64006400u | ((q >> 20) & 0xFu) | ( q         & 0xF0000u);
  w.u[2] = 0x64006400u | ((q >> 12) & 0xFu) | ((q << 8)  & 0xF0000u);
  w.u[3] = 0x64006400u | ((q >> 4)  & 0xFu) | ((q << 16) & 0xF0000u);
  half8 hv = w.h;
  half8 mm, ss;
  #pragma unroll
  for (int i = 0; i < 8; ++i) { mm[i] = (_Float16)(-1024.0f); ss[i] = sh; }
  return (hv + mm) * ss;   // pk_add_f16 + pk_mul_f16, vectorized
}

// Merged prep: blocks [0,8192) convert X f32->f16; blocks [8192,32768)
// dequantize W (one thread per packed int32 -> 16 B f16 store).
__global__ __launch_bounds__(256) void prep(const float* __restrict__ X,
                                            _Float16* __restrict__ XH,
                                            const int* __restrict__ Q,
                                            const float* __restrict__ S,
                                            _Float16* __restrict__ WH) {
  const int bid = blockIdx.x;
  if (bid < 8192) {
    const size_t i = ((size_t)bid * 256 + threadIdx.x) * 8;
    f32x4 v0 = *(const f32x4*)(X + i);
    f32x4 v1 = *(const f32x4*)(X + i + 4);
    union { fp16x2 h2[4]; half8 h8; } u;
    u.h2[0] = __builtin_amdgcn_cvt_pkrtz(v0.x, v0.y);
    u.h2[1] = __builtin_amdgcn_cvt_pkrtz(v0.z, v0.w);
    u.h2[2] = __builtin_amdgcn_cvt_pkrtz(v1.x, v1.y);
    u.h2[3] = __builtin_amdgcn_cvt_pkrtz(v1.z, v1.w);
    *(half8*)(XH + i) = u.h8;
  } else {
    const int idx = (bid - 8192) * 256 + threadIdx.x;  // [0, 12288*512)
    const int o = idx >> 9;    // output row (O)
    const int c = idx & 511;   // chunk within row (I/8)
    const uint32_t q = (uint32_t)Q[idx];
    const float s = S[o * (K_DIM / 128) + (c >> 4)];
    *(half8*)(WH + (size_t)o * K_DIM + c * 8) = dequant8(q, (_Float16)s);
  }
}

// f32->f16 only (fallback path)
__global__ __launch_bounds__(256) void cvt_f32_f16(const float* __restrict__ X,
                                                   _Float16* __restrict__ XH) {
  const size_t i = ((size_t)blockIdx.x * 256 + threadIdx.x) * 8;
  f32x4 v0 = *(const f32x4*)(X + i);
  f32x4 v1 = *(const f32x4*)(X + i + 4);
  union { fp16x2 h2[4]; half8 h8; } u;
  u.h2[0] = __builtin_amdgcn_cvt_pkrtz(v0.x, v0.y);
  u.h2[1] = __builtin_amdgcn_cvt_pkrtz(v0.z, v0.w);
  u.h2[2] = __builtin_amdgcn_cvt_pkrtz(v1.x, v1.y);
  u.h2[3] = __builtin_amdgcn_cvt_pkrtz(v1.z, v1.w);
  *(half8*)(XH + i) = u.h8;
}

// ==================== 256x256 6-phase GEMM (T2+T3+T4+T5) =====================
// 512 threads = 8 waves (2M x 4N), per-wave output 128x64.
// Core: mfma_f32_16x16x32_f16 (R6 falsified 32x32: 4-way bank conflict).
//
// R9 (two edits on the verified R8 schedule):
//  (a) hoisted reads now sit BETWEEN the post-barrier lgkmcnt(0) and the MFMA
//      burst: ~12 cyc of issue, then the LDS pipe drains them UNDER the
//      ~600-cyc MFMA burst (R8 had them after the burst -> LDS idle during it).
//  (b) read-free phases merged: P3+P4 -> P34, P7+P8 -> P78 (stages issue
//      together, one barrier pair each). 4 fewer s_barriers/iteration.
//
// LDS: double-buffered A/B K-tiles (BK=64) = 128 KiB.
// READ-COMPLETION LEDGER (last ds_read of each region):
//   buf0 As: P2-region (hoisted a2)   buf0 Bs: P1-region (hoisted bh)
//   buf1 As: P6-region (hoisted a2)   buf1 Bs: P5-region (hoisted bh)
// Stage slots (each >=1 barrier after the last read of its target):
//   P1/P2: A(odd)->buf1            [buf1 As read-done prev P6; P78+P1 barriers]
//   P34:   B(next even)->buf0 x2   [buf0 Bs read-done P1; P2 barrier between]
//   P5/P6: A(next even)->buf0      [buf0 As read-done P2; P34 barriers between]
//   P78:   B(next odd)->buf1 x2    [buf1 Bs read-done P5; P6 barrier between]
// vmcnt ledger (per wave):
//   P34 end: outstanding = its own 4 loads -> vmcnt(4) proves P1/P2 A-odd
//            (and older) landed before P5 reads buf1.
//   P78 end: outstanding = its own 4 loads -> vmcnt(4) proves P34 B-even +
//            P5/P6 A-even landed before next P1 reads buf0.
//   (vmcnt is PER-WAVE: publication = {all waves' wait} + barrier.)
// lgkm policy: explicit lgkmcnt(0)+sched_barrier(0) after each phase barrier
// (R5 falsified removal: +21 us; R7 falsified pre-barrier lgkmcnt(8): +20 us).
// Swizzle: LDS chunk index XOR (row&7); inverse on the global SOURCE address.
// Locality: m-fastest block order (FETCH 841->447 MB, R4); plain C stores
// (nt-stores bypassed L2 write-merge: +26 MB WRITE, slower, R4).

#define WAIT_LGKM0()                                                          \
  do { asm volatile("s_waitcnt lgkmcnt(0)" ::: "memory");                     \
       __builtin_amdgcn_sched_barrier(0); } while (0)
#define WAIT_VM4()                                                            \
  do { asm volatile("s_waitcnt vmcnt(4)" ::: "memory");                       \
       __builtin_amdgcn_sched_barrier(0); } while (0)
#define BARX() __builtin_amdgcn_s_barrier()

#define LDA4(dst, buf, mib)                                                   \
  _Pragma("unroll") for (int j = 0; j < 4; ++j) {                             \
    const int row_ = wm + ((mib) + j) * 16 + rrow;                            \
    dst[j][0] = As[buf][row_ * 8 + (quad ^ (row_ & 7))];                      \
    dst[j][1] = As[buf][row_ * 8 + ((quad + 4) ^ (row_ & 7))];                \
  }

#define LDB2(bb, buf, nib)                                                    \
  _Pragma("unroll") for (int j = 0; j < 2; ++j) {                             \
    const int row_ = wn + ((nib) + j) * 16 + rrow;                            \
    bb[j][0] = Bs[buf][row_ * 8 + (quad ^ (row_ & 7))];                       \
    bb[j][1] = Bs[buf][row_ * 8 + ((quad + 4) ^ (row_ & 7))];                 \
  }

#define MFMAQ(aa, mb, nb, bb)                                                 \
  do {                                                                        \
    __builtin_amdgcn_s_setprio(1);                                            \
    _Pragma("unroll") for (int mi = 0; mi < 4; ++mi)                          \
      _Pragma("unroll") for (int ni = 0; ni < 2; ++ni)                        \
        _Pragma("unroll") for (int kk = 0; kk < 2; ++kk)                      \
          acc[(mb) + mi][(nb) + ni] = __builtin_amdgcn_mfma_f32_16x16x32_f16( \
              aa[mi][kk], bb[ni][kk], acc[(mb) + mi][(nb) + ni], 0, 0, 0);    \
    __builtin_amdgcn_s_setprio(0);                                            \
  } while (0)

#define STAGE_A(buf, h, koff)                                                 \
  do {                                                                        \
    GLOAD_LDS16(XH + aOff[h][0] + (koff), &As[buf][(h)*1024 + wave * 64]);    \
    GLOAD_LDS16(XH + aOff[h][1] + (koff), &As[buf][(h)*1024 + 512 + wave*64]);\
  } while (0)
#define STAGE_B(buf, h, koff)                                                 \
  do {                                                                        \
    GLOAD_LDS16(WH + bOff[h][0] + (koff), &Bs[buf][(h)*1024 + wave * 64]);    \
    GLOAD_LDS16(WH + bOff[h][1] + (koff), &Bs[buf][(h)*1024 + 512 + wave*64]);\
  } while (0)

__global__ __launch_bounds__(512, 2) void gemm_f16_8p(
    const _Float16* __restrict__ XH, const _Float16* __restrict__ WH,
    const float* __restrict__ Bias, float* __restrict__ C) {
  __shared__ half8 As[2][2048];   // [buf][row*8 + swz-chunk], 256 rows x 64 k
  __shared__ half8 Bs[2][2048];

  const int tid  = threadIdx.x;
  const int lane = tid & 63;
  const int wave = tid >> 6;
  const int wm   = (wave >> 2) * 128;  // wave M origin within tile
  const int wn   = (wave & 3) * 64;    // wave N origin within tile
  const int rrow = lane & 15;
  const int quad = lane >> 4;

  // XCD-aware bijective swizzle: 768 blocks, 768 % 8 == 0.
  // m-FASTEST order: concurrent blocks cover all 16 m-tiles (A L3-resident)
  // and cluster the 16 readers of each W n-panel close in time.
  const int bid = blockIdx.x;
  const int swz = (bid & 7) * 96 + (bid >> 3);
  const int m0  = (swz & 15) * 256;   // 16 m-tiles, fastest
  const int n0  = (swz >> 4) * 256;   // 48 n-tiles

  // Per-lane inverse-swizzled global source offsets (elements).
  // LDS slot s = r*512 + tid within a 128-row half; row = s>>3,
  // global chunk c = (s&7) ^ (row&7).
  uint32_t aOff[2][2], bOff[2][2];
  #pragma unroll
  for (int h = 0; h < 2; ++h)
    #pragma unroll
    for (int r = 0; r < 2; ++r) {
      const int slot = r * 512 + tid;
      const int row  = slot >> 3;
      const int c    = (slot & 7) ^ (row & 7);
      aOff[h][r] = (uint32_t)((m0 + h * 128 + row) * K_DIM + c * 8);
      bOff[h][r] = (uint32_t)((n0 + h * 128 + row) * K_DIM + c * 8);
    }

  f32x4 acc[8][4];
  #pragma unroll
  for (int i = 0; i < 8; ++i)
    #pragma unroll
    for (int j = 0; j < 4; ++j)
      acc[i][j] = (f32x4){0.f, 0.f, 0.f, 0.f};

  half8 a[4][2], a2[4][2], bl[2][2], bh[2][2];

  // Prologue ("iteration -1" slots): tile0 fully -> buf0 (8 loads, oldest),
  // then tile1 B -> buf1 (4 loads). vmcnt(4) -> tile0's 8 landed.
  STAGE_B(0, 0, 0);  STAGE_B(0, 1, 0);  STAGE_A(0, 0, 0);  STAGE_A(0, 1, 0);
  STAGE_B(1, 0, 64); STAGE_B(1, 1, 64);
  WAIT_VM4();
  BARX();

  // 32 iterations x 2 K-tiles (NT = 64).
  for (int it = 0; it < 32; ++it) {
    const int k1  = it * 128 + 64;                  // current odd tile
    const int kp0 = (it < 31) ? it * 128 + 128 : 0; // prefetch tile 2it+2
    const int kp1 = (it < 31) ? it * 128 + 192 : 0; // prefetch tile 2it+3

    // P1: (Mlo,Nlo) of buf0; stage A-h0(current odd) -> buf1.
    // Hoisted bh reads issue FIRST post-wait, drain under the MFMA burst.
    LDA4(a, 0, 0);
    LDB2(bl, 0, 0);
    STAGE_A(1, 0, k1);
    BARX(); WAIT_LGKM0();
    LDB2(bh, 0, 2);
    MFMAQ(a, 0, 0, bl);
    BARX();

    // P2: (Mlo,Nhi); stage A-h1(current odd) -> buf1.
    // Hoisted a2 reads issue first, drain under the MFMA burst.
    STAGE_A(1, 1, k1);
    BARX(); WAIT_LGKM0();
    LDA4(a2, 0, 4);
    MFMAQ(a, 0, 2, bh);
    BARX();

    // P34 (merged): (Mhi,Nhi)+(Mhi,Nlo); stage both B(next even) halves ->
    // buf0 [buf0 Bs read-done P1, P2 barrier between]. vmcnt(4): outstanding
    // = own 4 loads -> P1/P2 A-odd landed before P5 reads buf1.
    STAGE_B(0, 0, kp0);
    STAGE_B(0, 1, kp0);
    BARX(); WAIT_LGKM0();
    MFMAQ(a2, 4, 2, bh);
    MFMAQ(a2, 4, 0, bl);
    WAIT_VM4();
    BARX();

    // P5: (Mlo,Nlo) of buf1; stage A-h0(next even) -> buf0 [read-done P2].
    LDA4(a, 1, 0);
    LDB2(bl, 1, 0);
    STAGE_A(0, 0, kp0);
    BARX(); WAIT_LGKM0();
    LDB2(bh, 1, 2);
    MFMAQ(a, 0, 0, bl);
    BARX();

    // P6: (Mlo,Nhi); stage A-h1(next even) -> buf0.
    STAGE_A(0, 1, kp0);
    BARX(); WAIT_LGKM0();
    LDA4(a2, 1, 4);
    MFMAQ(a, 0, 2, bh);
    BARX();

    // P78 (merged): (Mhi,Nhi)+(Mhi,Nlo); stage both B(next odd) halves ->
    // buf1 [buf1 Bs read-done P5, P6 barrier between]. vmcnt(4): outstanding
    // = own 4 loads -> P34 B-even + P5/P6 A-even landed before next P1.
    STAGE_B(1, 0, kp1);
    STAGE_B(1, 1, kp1);
    BARX(); WAIT_LGKM0();
    MFMAQ(a2, 4, 2, bh);
    MFMAQ(a2, 4, 0, bl);
    WAIT_VM4();
    BARX();
  }

  // Epilogue: C/D layout col(n)=lane&15, row(m)=quad*4+reg [m89].
  // Plain stores (nt-stores: +26 MB WRITE_SIZE, slower — R4).
  #pragma unroll
  for (int ni = 0; ni < 4; ++ni) {
    const int n = n0 + wn + ni * 16 + rrow;
    const float bv = Bias[n];
    #pragma unroll
    for (int mi = 0; mi < 8; ++mi) {
      const int mbase = m0 + wm + mi * 16 + quad * 4;
      #pragma unroll
      for (int rr = 0; rr < 4; ++rr) {
        C[(size_t)(mbase + rr) * N_DIM + n] = acc[mi][ni][rr] + bv;
      }
    }
  }
}

// ---------------- fallback (previous verified 128^2 kernel) ----------------
template <bool PRE>
__global__ __launch_bounds__(256) void awq_gemm(
    const float* __restrict__ X, const _Float16* __restrict__ XH,
    const int* __restrict__ Q, const float* __restrict__ S,
    const float* __restrict__ Bias, float* __restrict__ C) {
  __shared__ half8 Asf[BM * 8];
  __shared__ half8 Bsf[BN * 8];

  const int tid  = threadIdx.x;
  const int lane = tid & 63;
  const int wave = tid >> 6;
  const int wm   = (wave >> 1) * 64;
  const int wn   = (wave & 1) * 64;
  const int m0   = blockIdx.y * BM;
  const int n0   = blockIdx.x * BN;
  const int rrow = lane & 15;
  const int quad = lane >> 4;

  const _Float16* a_gp[4];
  if (PRE) {
    #pragma unroll
    for (int r = 0; r < 4; ++r) {
      const int slot = (wave * 4 + r) * 64 + lane;
      const int row  = slot >> 3;
      const int c    = (slot & 7) ^ (row & 7);
      a_gp[r] = XH + (size_t)(m0 + row) * K_DIM + c * 8;
    }
  }

  int brow[4], bcol[4];
  #pragma unroll
  for (int r = 0; r < 4; ++r) {
    const int idx = tid + 256 * r;
    brow[r] = idx >> 3;
    bcol[r] = idx & 7;
  }

  f32x4 acc[4][4];
  #pragma unroll
  for (int i = 0; i < 4; ++i)
    #pragma unroll
    for (int j = 0; j < 4; ++j)
      acc[i][j] = (f32x4){0.f, 0.f, 0.f, 0.f};

  for (int k0 = 0; k0 < K_DIM; k0 += BK) {
    if (PRE) {
      #pragma unroll
      for (int r = 0; r < 4; ++r)
        GLOAD_LDS16(a_gp[r] + k0, &Asf[(wave * 4 + r) * 64]);
    } else {
      #pragma unroll
      for (int r = 0; r < 4; ++r) {
        const int ch  = tid + 256 * r;
        const int row = ch >> 3;
        const int c   = ch & 7;
        const float* p = X + (size_t)(m0 + row) * K_DIM + k0 + c * 8;
        f32x4 v0 = *(const f32x4*)p;
        f32x4 v1 = *(const f32x4*)(p + 4);
        union { fp16x2 h2[4]; half8 h8; } u;
        u.h2[0] = __builtin_amdgcn_cvt_pkrtz(v0.x, v0.y);
        u.h2[1] = __builtin_amdgcn_cvt_pkrtz(v0.z, v0.w);
        u.h2[2] = __builtin_amdgcn_cvt_pkrtz(v1.x, v1.y);
        u.h2[3] = __builtin_amdgcn_cvt_pkrtz(v1.z, v1.w);
        Asf[row * 8 + (c ^ (row & 7))] = u.h8;
      }
    }
    #pragma unroll
    for (int r = 0; r < 4; ++r) {
      const int row = brow[r];
      const int c   = bcol[r];
      const uint32_t q =
          (uint32_t)Q[(size_t)(n0 + row) * (K_DIM / 8) + (k0 >> 3) + c];
      const float s = S[(size_t)(n0 + row) * (K_DIM / 128) + (k0 >> 7)];
      Bsf[row * 8 + (c ^ (row & 7))] = dequant8(q, (_Float16)s);
    }
    __syncthreads();

    #pragma unroll
    for (int kk = 0; kk < 2; ++kk) {
      const int kch = kk * 4 + quad;
      half8 a[4], b[4];
      #pragma unroll
      for (int mi = 0; mi < 4; ++mi) {
        const int row = wm + mi * 16 + rrow;
        a[mi] = Asf[row * 8 + (kch ^ (row & 7))];
      }
      #pragma unroll
      for (int ni = 0; ni < 4; ++ni) {
        const int row = wn + ni * 16 + rrow;
        b[ni] = Bsf[row * 8 + (kch ^ (row & 7))];
      }
      #pragma unroll
      for (int mi = 0; mi < 4; ++mi)
        #pragma unroll
        for (int ni = 0; ni < 4; ++ni)
          acc[mi][ni] = __builtin_amdgcn_mfma_f32_16x16x32_f16(
              a[mi], b[ni], acc[mi][ni], 0, 0, 0);
    }
    __syncthreads();
  }

  #pragma unroll
  for (int ni = 0; ni < 4; ++ni) {
    const int n = n0 + wn + ni * 16 + rrow;
    const float bv = Bias[n];
    #pragma unroll
    for (int mi = 0; mi < 4; ++mi) {
      const int mbase = m0 + wm + mi * 16 + quad * 4;
      #pragma unroll
      for (int rr = 0; rr < 4; ++rr) {
        C[(size_t)(mbase + rr) * N_DIM + n] = acc[mi][ni][rr] + bv;
      }
    }
  }
}

extern "C" void kernel_launch(void* const* d_in, const int* in_sizes, int n_in,
                              void* d_out, int out_size, void* d_ws, size_t ws_size,
                              hipStream_t stream) {
  const float* X    = (const float*)d_in[0];
  const int*   Q    = (const int*)d_in[1];
  const float* S    = (const float*)d_in[2];
  const float* Bias = (const float*)d_in[3];
  float* C = (float*)d_out;

  const size_t needXH = (size_t)M_DIM * K_DIM * sizeof(_Float16);  // 32 MiB
  const size_t needWH = (size_t)N_DIM * K_DIM * sizeof(_Float16);  // 96 MiB
  if (ws_size >= needXH + needWH) {
    _Float16* XH = (_Float16*)d_ws;
    _Float16* WH = (_Float16*)((char*)d_ws + needXH);
    prep<<<dim3(8192 + 24576), dim3(256), 0, stream>>>(X, XH, Q, S, WH);
    gemm_f16_8p<<<dim3(768), dim3(512), 0, stream>>>(XH, WH, Bias, C);
  } else if (ws_size >= needXH) {
    _Float16* XH = (_Float16*)d_ws;
    cvt_f32_f16<<<(M_DIM * (size_t)K_DIM) / 8 / 256, 256, 0, stream>>>(X, XH);
    awq_gemm<true><<<dim3(N_DIM / BN, M_DIM / BM), dim3(256), 0, stream>>>(
        X, XH, Q, S, Bias, C);
  } else {
    awq_gemm<false><<<dim3(N_DIM / BN, M_DIM / BM), dim3(256), 0, stream>>>(
        X, nullptr, Q, S, Bias, C);
  }
}

// Round 10
// 646.058 us; speedup vs baseline: 1.0923x; 1.0923x over previous
//
#include <hip/hip_runtime.h>
#include <stdint.h>

#define M_DIM 4096
#define K_DIM 4096
#define N_DIM 12288

// fallback tile (old verified 128^2 kernel)
#define BM 128
#define BN 128
#define BK 64

typedef __attribute__((ext_vector_type(8))) _Float16 half8;
typedef __attribute__((ext_vector_type(2))) __fp16 fp16x2;
typedef __attribute__((ext_vector_type(4))) float f32x4;

#define GLOAD_LDS16(gp, lp)                                                   \
  __builtin_amdgcn_global_load_lds(                                           \
      (const __attribute__((address_space(1))) void*)(gp),                    \
      (__attribute__((address_space(3))) void*)(lp), 16, 0, 0)

// 8 nibbles (high-first) -> 8 f16 weights, single-rounded:
// h = 1024 + n exactly (0x6400|n); (h - 1024) is exact; one mul rounds.
static __device__ __forceinline__ half8 dequant8(uint32_t q, _Float16 sh) {
  union { uint32_t u[4]; half8 h; } w;
  w.u[0] = 0x64006400u | ((q >> 28) & 0xFu) | ((q >> 8)  & 0xF0000u);
  w.u[1] = 0x64006400u | ((q >> 20) & 0xFu) | ( q         & 0xF0000u);
  w.u[2] = 0x64006400u | ((q >> 12) & 0xFu) | ((q << 8)  & 0xF0000u);
  w.u[3] = 0x64006400u | ((q >> 4)  & 0xFu) | ((q << 16) & 0xF0000u);
  half8 hv = w.h;
  half8 mm, ss;
  #pragma unroll
  for (int i = 0; i < 8; ++i) { mm[i] = (_Float16)(-1024.0f); ss[i] = sh; }
  return (hv + mm) * ss;   // pk_add_f16 + pk_mul_f16, vectorized
}

// Merged prep: blocks [0,8192) convert X f32->f16; blocks [8192,32768)
// dequantize W (one thread per packed int32 -> 16 B f16 store).
__global__ __launch_bounds__(256) void prep(const float* __restrict__ X,
                                            _Float16* __restrict__ XH,
                                            const int* __restrict__ Q,
                                            const float* __restrict__ S,
                                            _Float16* __restrict__ WH) {
  const int bid = blockIdx.x;
  if (bid < 8192) {
    const size_t i = ((size_t)bid * 256 + threadIdx.x) * 8;
    f32x4 v0 = *(const f32x4*)(X + i);
    f32x4 v1 = *(const f32x4*)(X + i + 4);
    union { fp16x2 h2[4]; half8 h8; } u;
    u.h2[0] = __builtin_amdgcn_cvt_pkrtz(v0.x, v0.y);
    u.h2[1] = __builtin_amdgcn_cvt_pkrtz(v0.z, v0.w);
    u.h2[2] = __builtin_amdgcn_cvt_pkrtz(v1.x, v1.y);
    u.h2[3] = __builtin_amdgcn_cvt_pkrtz(v1.z, v1.w);
    *(half8*)(XH + i) = u.h8;
  } else {
    const int idx = (bid - 8192) * 256 + threadIdx.x;  // [0, 12288*512)
    const int o = idx >> 9;    // output row (O)
    const int c = idx & 511;   // chunk within row (I/8)
    const uint32_t q = (uint32_t)Q[idx];
    const float s = S[o * (K_DIM / 128) + (c >> 4)];
    *(half8*)(WH + (size_t)o * K_DIM + c * 8) = dequant8(q, (_Float16)s);
  }
}

// f32->f16 only (fallback path)
__global__ __launch_bounds__(256) void cvt_f32_f16(const float* __restrict__ X,
                                                   _Float16* __restrict__ XH) {
  const size_t i = ((size_t)blockIdx.x * 256 + threadIdx.x) * 8;
  f32x4 v0 = *(const f32x4*)(X + i);
  f32x4 v1 = *(const f32x4*)(X + i + 4);
  union { fp16x2 h2[4]; half8 h8; } u;
  u.h2[0] = __builtin_amdgcn_cvt_pkrtz(v0.x, v0.y);
  u.h2[1] = __builtin_amdgcn_cvt_pkrtz(v0.z, v0.w);
  u.h2[2] = __builtin_amdgcn_cvt_pkrtz(v1.x, v1.y);
  u.h2[3] = __builtin_amdgcn_cvt_pkrtz(v1.z, v1.w);
  *(half8*)(XH + i) = u.h8;
}

// ===================== 256x256 8-phase GEMM (T2+T3+T4+T5) =====================
// 512 threads = 8 waves (2M x 4N), per-wave output 128x64.
// Core: mfma_f32_16x16x32_f16 (R6 falsified 32x32: 4-way bank conflict).
//
// R8 (VERIFIED BEST, restored after R9 regression): hoisted reads for
// P2/P3/P6/P7 issue inside the PREVIOUS phase's post-lgkm region, AFTER its
// MFMA burst. R9 falsified both (a) reads-before-burst and (b) P3+P4/P7+P8
// phase merge: at __launch_bounds__(512,2) the unified reg file is 256/wave
// (acc=128 AGPR + ~128 VGPR, at the brim); R9's longer live ranges spilled
// to scratch (WRITE_SIZE 214->286 MB, FETCH +43 MB, MfmaUtil 48.5->36).
// At a hard register ceiling, schedule stretch = spill.
//
// Hoist hazards (all SAFE):
//   - P2's bh (buf0 Bs-hi): writer = P3/P4 stage. Read completes at P2's
//     lgkmcnt(0), which every wave passes BEFORE any wave reaches P3's stage
//     (P2 end-barrier orders it).
//   - P3's A-hi (buf0): writer = P5/P6 stage (further).
//   - P6/P7: mirror on buf1 (writers P7/P8 and next-P1/P2).
//   - P1/P5 reads CANNOT hoist: their buffer is published only by the
//     immediately preceding vmcnt(4)+barrier.
// Second A-frag set a2 resolves a-lo (used P2) vs a-hi (loading in P2's
// region) overlap. Lifetimes: a P1->P2, a2 P2->P4, bl P1->P4, bh P1->P3.
//
// LDS: double-buffered A/B K-tiles (BK=64) = 128 KiB.
// READ-COMPLETION LEDGER (last ds_read of each region, post-hoist):
//   buf0 As: P2-region (hoisted a2)   buf0 Bs: P1-region (hoisted bh)
//   buf1 As: P6-region (hoisted a2)   buf1 Bs: P5-region (hoisted bh)
// Stage slots (each >=1 barrier after last read of its target):
//   P1/P2: A(odd)->buf1   P3/P4: B(next even)->buf0
//   P5/P6: A(next even)->buf0   P7/P8: B(next odd)->buf1
// vmcnt ledger (2 loads per stage, per wave): vmcnt(4) at P4 (odd tile
// complete before P5 reads buf1) and P8 (even tile complete before next P1
// reads buf0). vmcnt is PER-WAVE: publication = {all waves' wait} + barrier.
// lgkm policy: explicit lgkmcnt(0)+sched_barrier(0) after each phase barrier
// (R5 falsified removal: +21 us; R7 falsified pre-barrier lgkmcnt(8): +20 us).
// Swizzle: LDS chunk index XOR (row&7); inverse on the global SOURCE address.
// Locality: m-fastest block order (FETCH 841->447 MB, R4); plain C stores
// (nt-stores bypassed L2 write-merge: +26 MB WRITE, slower, R4).

#define WAIT_LGKM0()                                                          \
  do { asm volatile("s_waitcnt lgkmcnt(0)" ::: "memory");                     \
       __builtin_amdgcn_sched_barrier(0); } while (0)
#define WAIT_VM4()                                                            \
  do { asm volatile("s_waitcnt vmcnt(4)" ::: "memory");                       \
       __builtin_amdgcn_sched_barrier(0); } while (0)
#define BARX() __builtin_amdgcn_s_barrier()

#define LDA4(dst, buf, mib)                                                   \
  _Pragma("unroll") for (int j = 0; j < 4; ++j) {                             \
    const int row_ = wm + ((mib) + j) * 16 + rrow;                            \
    dst[j][0] = As[buf][row_ * 8 + (quad ^ (row_ & 7))];                      \
    dst[j][1] = As[buf][row_ * 8 + ((quad + 4) ^ (row_ & 7))];                \
  }

#define LDB2(bb, buf, nib)                                                    \
  _Pragma("unroll") for (int j = 0; j < 2; ++j) {                             \
    const int row_ = wn + ((nib) + j) * 16 + rrow;                            \
    bb[j][0] = Bs[buf][row_ * 8 + (quad ^ (row_ & 7))];                       \
    bb[j][1] = Bs[buf][row_ * 8 + ((quad + 4) ^ (row_ & 7))];                 \
  }

#define MFMAQ(aa, mb, nb, bb)                                                 \
  do {                                                                        \
    __builtin_amdgcn_s_setprio(1);                                            \
    _Pragma("unroll") for (int mi = 0; mi < 4; ++mi)                          \
      _Pragma("unroll") for (int ni = 0; ni < 2; ++ni)                        \
        _Pragma("unroll") for (int kk = 0; kk < 2; ++kk)                      \
          acc[(mb) + mi][(nb) + ni] = __builtin_amdgcn_mfma_f32_16x16x32_f16( \
              aa[mi][kk], bb[ni][kk], acc[(mb) + mi][(nb) + ni], 0, 0, 0);    \
    __builtin_amdgcn_s_setprio(0);                                            \
  } while (0)

#define STAGE_A(buf, h, koff)                                                 \
  do {                                                                        \
    GLOAD_LDS16(XH + aOff[h][0] + (koff), &As[buf][(h)*1024 + wave * 64]);    \
    GLOAD_LDS16(XH + aOff[h][1] + (koff), &As[buf][(h)*1024 + 512 + wave*64]);\
  } while (0)
#define STAGE_B(buf, h, koff)                                                 \
  do {                                                                        \
    GLOAD_LDS16(WH + bOff[h][0] + (koff), &Bs[buf][(h)*1024 + wave * 64]);    \
    GLOAD_LDS16(WH + bOff[h][1] + (koff), &Bs[buf][(h)*1024 + 512 + wave*64]);\
  } while (0)

__global__ __launch_bounds__(512, 2) void gemm_f16_8p(
    const _Float16* __restrict__ XH, const _Float16* __restrict__ WH,
    const float* __restrict__ Bias, float* __restrict__ C) {
  __shared__ half8 As[2][2048];   // [buf][row*8 + swz-chunk], 256 rows x 64 k
  __shared__ half8 Bs[2][2048];

  const int tid  = threadIdx.x;
  const int lane = tid & 63;
  const int wave = tid >> 6;
  const int wm   = (wave >> 2) * 128;  // wave M origin within tile
  const int wn   = (wave & 3) * 64;    // wave N origin within tile
  const int rrow = lane & 15;
  const int quad = lane >> 4;

  // XCD-aware bijective swizzle: 768 blocks, 768 % 8 == 0.
  // m-FASTEST order: concurrent blocks cover all 16 m-tiles (A L3-resident)
  // and cluster the 16 readers of each W n-panel close in time.
  const int bid = blockIdx.x;
  const int swz = (bid & 7) * 96 + (bid >> 3);
  const int m0  = (swz & 15) * 256;   // 16 m-tiles, fastest
  const int n0  = (swz >> 4) * 256;   // 48 n-tiles

  // Per-lane inverse-swizzled global source offsets (elements).
  // LDS slot s = r*512 + tid within a 128-row half; row = s>>3,
  // global chunk c = (s&7) ^ (row&7).
  uint32_t aOff[2][2], bOff[2][2];
  #pragma unroll
  for (int h = 0; h < 2; ++h)
    #pragma unroll
    for (int r = 0; r < 2; ++r) {
      const int slot = r * 512 + tid;
      const int row  = slot >> 3;
      const int c    = (slot & 7) ^ (row & 7);
      aOff[h][r] = (uint32_t)((m0 + h * 128 + row) * K_DIM + c * 8);
      bOff[h][r] = (uint32_t)((n0 + h * 128 + row) * K_DIM + c * 8);
    }

  f32x4 acc[8][4];
  #pragma unroll
  for (int i = 0; i < 8; ++i)
    #pragma unroll
    for (int j = 0; j < 4; ++j)
      acc[i][j] = (f32x4){0.f, 0.f, 0.f, 0.f};

  half8 a[4][2], a2[4][2], bl[2][2], bh[2][2];

  // Prologue ("iteration -1" P3..P8): tile0 fully -> buf0 (8 loads, oldest),
  // then tile1 B -> buf1 (4 loads). vmcnt(4) -> tile0's 8 landed.
  STAGE_B(0, 0, 0);  STAGE_B(0, 1, 0);  STAGE_A(0, 0, 0);  STAGE_A(0, 1, 0);
  STAGE_B(1, 0, 64); STAGE_B(1, 1, 64);
  WAIT_VM4();
  BARX();

  // 32 iterations x 2 K-tiles (NT = 64).
  for (int it = 0; it < 32; ++it) {
    const int k1  = it * 128 + 64;                  // current odd tile
    const int kp0 = (it < 31) ? it * 128 + 128 : 0; // prefetch tile 2it+2
    const int kp1 = (it < 31) ? it * 128 + 192 : 0; // prefetch tile 2it+3

    // P1: (Mlo,Nlo) of buf0; stage A-h0(current odd) -> buf1.
    // Post-MFMA: hoist P2's bh reads (interleave with MFMA issue).
    LDA4(a, 0, 0);
    LDB2(bl, 0, 0);
    STAGE_A(1, 0, k1);
    BARX(); WAIT_LGKM0();
    MFMAQ(a, 0, 0, bl);
    LDB2(bh, 0, 2);
    BARX();

    // P2: (Mlo,Nhi); stage A-h1(current odd) -> buf1.
    // Post-MFMA: hoist P3/P4's A-hi reads into a2.
    STAGE_A(1, 1, k1);
    BARX(); WAIT_LGKM0();
    MFMAQ(a, 0, 2, bh);
    LDA4(a2, 0, 4);
    BARX();

    // P3: (Mhi,Nhi) from a2; stage B-h0(next even) -> buf0 [buf0 Bs read-done P1]
    STAGE_B(0, 0, kp0);
    BARX(); WAIT_LGKM0();
    MFMAQ(a2, 4, 2, bh);
    BARX();

    // P4: (Mhi,Nlo) from regs; stage B-h1(next even) -> buf0; vmcnt(4)
    // -> odd tile (prev P7/P8 B + P1/P2 A) fully landed before P5 reads.
    STAGE_B(0, 1, kp0);
    BARX();
    MFMAQ(a2, 4, 0, bl);
    WAIT_VM4();
    BARX();

    // P5: (Mlo,Nlo) of buf1; stage A-h0(next even) -> buf0 [buf0 As read-done P2]
    // Post-MFMA: hoist P6's bh reads.
    LDA4(a, 1, 0);
    LDB2(bl, 1, 0);
    STAGE_A(0, 0, kp0);
    BARX(); WAIT_LGKM0();
    MFMAQ(a, 0, 0, bl);
    LDB2(bh, 1, 2);
    BARX();

    // P6: (Mlo,Nhi); stage A-h1(next even) -> buf0.
    // Post-MFMA: hoist P7/P8's A-hi reads into a2.
    STAGE_A(0, 1, kp0);
    BARX(); WAIT_LGKM0();
    MFMAQ(a, 0, 2, bh);
    LDA4(a2, 1, 4);
    BARX();

    // P7: (Mhi,Nhi) from a2; stage B-h0(next odd) -> buf1 [buf1 Bs read-done P5]
    STAGE_B(1, 0, kp1);
    BARX(); WAIT_LGKM0();
    MFMAQ(a2, 4, 2, bh);
    BARX();

    // P8: (Mhi,Nlo) from regs; stage B-h1(next odd) -> buf1; vmcnt(4)
    // -> next even tile (P3..P6 stages, buf0) landed before next P1 reads.
    STAGE_B(1, 1, kp1);
    BARX();
    MFMAQ(a2, 4, 0, bl);
    WAIT_VM4();
    BARX();
  }

  // Epilogue: C/D layout col(n)=lane&15, row(m)=quad*4+reg [m89].
  // Plain stores (nt-stores: +26 MB WRITE_SIZE, slower — R4).
  #pragma unroll
  for (int ni = 0; ni < 4; ++ni) {
    const int n = n0 + wn + ni * 16 + rrow;
    const float bv = Bias[n];
    #pragma unroll
    for (int mi = 0; mi < 8; ++mi) {
      const int mbase = m0 + wm + mi * 16 + quad * 4;
      #pragma unroll
      for (int rr = 0; rr < 4; ++rr) {
        C[(size_t)(mbase + rr) * N_DIM + n] = acc[mi][ni][rr] + bv;
      }
    }
  }
}

// ---------------- fallback (previous verified 128^2 kernel) ----------------
template <bool PRE>
__global__ __launch_bounds__(256) void awq_gemm(
    const float* __restrict__ X, const _Float16* __restrict__ XH,
    const int* __restrict__ Q, const float* __restrict__ S,
    const float* __restrict__ Bias, float* __restrict__ C) {
  __shared__ half8 Asf[BM * 8];
  __shared__ half8 Bsf[BN * 8];

  const int tid  = threadIdx.x;
  const int lane = tid & 63;
  const int wave = tid >> 6;
  const int wm   = (wave >> 1) * 64;
  const int wn   = (wave & 1) * 64;
  const int m0   = blockIdx.y * BM;
  const int n0   = blockIdx.x * BN;
  const int rrow = lane & 15;
  const int quad = lane >> 4;

  const _Float16* a_gp[4];
  if (PRE) {
    #pragma unroll
    for (int r = 0; r < 4; ++r) {
      const int slot = (wave * 4 + r) * 64 + lane;
      const int row  = slot >> 3;
      const int c    = (slot & 7) ^ (row & 7);
      a_gp[r] = XH + (size_t)(m0 + row) * K_DIM + c * 8;
    }
  }

  int brow[4], bcol[4];
  #pragma unroll
  for (int r = 0; r < 4; ++r) {
    const int idx = tid + 256 * r;
    brow[r] = idx >> 3;
    bcol[r] = idx & 7;
  }

  f32x4 acc[4][4];
  #pragma unroll
  for (int i = 0; i < 4; ++i)
    #pragma unroll
    for (int j = 0; j < 4; ++j)
      acc[i][j] = (f32x4){0.f, 0.f, 0.f, 0.f};

  for (int k0 = 0; k0 < K_DIM; k0 += BK) {
    if (PRE) {
      #pragma unroll
      for (int r = 0; r < 4; ++r)
        GLOAD_LDS16(a_gp[r] + k0, &Asf[(wave * 4 + r) * 64]);
    } else {
      #pragma unroll
      for (int r = 0; r < 4; ++r) {
        const int ch  = tid + 256 * r;
        const int row = ch >> 3;
        const int c   = ch & 7;
        const float* p = X + (size_t)(m0 + row) * K_DIM + k0 + c * 8;
        f32x4 v0 = *(const f32x4*)p;
        f32x4 v1 = *(const f32x4*)(p + 4);
        union { fp16x2 h2[4]; half8 h8; } u;
        u.h2[0] = __builtin_amdgcn_cvt_pkrtz(v0.x, v0.y);
        u.h2[1] = __builtin_amdgcn_cvt_pkrtz(v0.z, v0.w);
        u.h2[2] = __builtin_amdgcn_cvt_pkrtz(v1.x, v1.y);
        u.h2[3] = __builtin_amdgcn_cvt_pkrtz(v1.z, v1.w);
        Asf[row * 8 + (c ^ (row & 7))] = u.h8;
      }
    }
    #pragma unroll
    for (int r = 0; r < 4; ++r) {
      const int row = brow[r];
      const int c   = bcol[r];
      const uint32_t q =
          (uint32_t)Q[(size_t)(n0 + row) * (K_DIM / 8) + (k0 >> 3) + c];
      const float s = S[(size_t)(n0 + row) * (K_DIM / 128) + (k0 >> 7)];
      Bsf[row * 8 + (c ^ (row & 7))] = dequant8(q, (_Float16)s);
    }
    __syncthreads();

    #pragma unroll
    for (int kk = 0; kk < 2; ++kk) {
      const int kch = kk * 4 + quad;
      half8 a[4], b[4];
      #pragma unroll
      for (int mi = 0; mi < 4; ++mi) {
        const int row = wm + mi * 16 + rrow;
        a[mi] = Asf[row * 8 + (kch ^ (row & 7))];
      }
      #pragma unroll
      for (int ni = 0; ni < 4; ++ni) {
        const int row = wn + ni * 16 + rrow;
        b[ni] = Bsf[row * 8 + (kch ^ (row & 7))];
      }
      #pragma unroll
      for (int mi = 0; mi < 4; ++mi)
        #pragma unroll
        for (int ni = 0; ni < 4; ++ni)
          acc[mi][ni] = __builtin_amdgcn_mfma_f32_16x16x32_f16(
              a[mi], b[ni], acc[mi][ni], 0, 0, 0);
    }
    __syncthreads();
  }

  #pragma unroll
  for (int ni = 0; ni < 4; ++ni) {
    const int n = n0 + wn + ni * 16 + rrow;
    const float bv = Bias[n];
    #pragma unroll
    for (int mi = 0; mi < 4; ++mi) {
      const int mbase = m0 + wm + mi * 16 + quad * 4;
      #pragma unroll
      for (int rr = 0; rr < 4; ++rr) {
        C[(size_t)(mbase + rr) * N_DIM + n] = acc[mi][ni][rr] + bv;
      }
    }
  }
}

extern "C" void kernel_launch(void* const* d_in, const int* in_sizes, int n_in,
                              void* d_out, int out_size, void* d_ws, size_t ws_size,
                              hipStream_t stream) {
  const float* X    = (const float*)d_in[0];
  const int*   Q    = (const int*)d_in[1];
  const float* S    = (const float*)d_in[2];
  const float* Bias = (const float*)d_in[3];
  float* C = (float*)d_out;

  const size_t needXH = (size_t)M_DIM * K_DIM * sizeof(_Float16);  // 32 MiB
  const size_t needWH = (size_t)N_DIM * K_DIM * sizeof(_Float16);  // 96 MiB
  if (ws_size >= needXH + needWH) {
    _Float16* XH = (_Float16*)d_ws;
    _Float16* WH = (_Float16*)((char*)d_ws + needXH);
    prep<<<dim3(8192 + 24576), dim3(256), 0, stream>>>(X, XH, Q, S, WH);
    gemm_f16_8p<<<dim3(768), dim3(512), 0, stream>>>(XH, WH, Bias, C);
  } else if (ws_size >= needXH) {
    _Float16* XH = (_Float16*)d_ws;
    cvt_f32_f16<<<(M_DIM * (size_t)K_DIM) / 8 / 256, 256, 0, stream>>>(X, XH);
    awq_gemm<true><<<dim3(N_DIM / BN, M_DIM / BM), dim3(256), 0, stream>>>(
        X, XH, Q, S, Bias, C);
  } else {
    awq_gemm<false><<<dim3(N_DIM / BN, M_DIM / BM), dim3(256), 0, stream>>>(
        X, nullptr, Q, S, Bias, C);
  }
}

// Round 11
// 620.418 us; speedup vs baseline: 1.1374x; 1.0413x over previous
//
#include <hip/hip_runtime.h>
#include <stdint.h>

#define M_DIM 4096
#define K_DIM 4096
#define N_DIM 12288

// fallback tile (old verified 128^2 kernel)
#define BM 128
#define BN 128
#define BK 64

typedef __attribute__((ext_vector_type(8))) _Float16 half8;
typedef __attribute__((ext_vector_type(2))) __fp16 fp16x2;
typedef __attribute__((ext_vector_type(4))) float f32x4;

#define GLOAD_LDS16(gp, lp)                                                   \
  __builtin_amdgcn_global_load_lds(                                           \
      (const __attribute__((address_space(1))) void*)(gp),                    \
      (__attribute__((address_space(3))) void*)(lp), 16, 0, 0)

// 8 nibbles (high-first) -> 8 f16 weights, single-rounded:
// h = 1024 + n exactly (0x6400|n); (h - 1024) is exact; one mul rounds.
static __device__ __forceinline__ half8 dequant8(uint32_t q, _Float16 sh) {
  union { uint32_t u[4]; half8 h; } w;
  w.u[0] = 0x64006400u | ((q >> 28) & 0xFu) | ((q >> 8)  & 0xF0000u);
  w.u[1] = 0x64006400u | ((q >> 20) & 0xFu) | ( q         & 0xF0000u);
  w.u[2] = 0x64006400u | ((q >> 12) & 0xFu) | ((q << 8)  & 0xF0000u);
  w.u[3] = 0x64006400u | ((q >> 4)  & 0xFu) | ((q << 16) & 0xF0000u);
  half8 hv = w.h;
  half8 mm, ss;
  #pragma unroll
  for (int i = 0; i < 8; ++i) { mm[i] = (_Float16)(-1024.0f); ss[i] = sh; }
  return (hv + mm) * ss;   // pk_add_f16 + pk_mul_f16, vectorized
}

// Merged prep (R11: W-part vectorized per G13):
//   blocks [0,8192): convert X f32->f16, 8 floats/thread.
//   blocks [8192,20480): dequant W, int2 Q load (8 B) -> 2 chunks -> 32 B
//   of f16 per thread. Chunk pair (2c2, 2c2+1) always shares a scale group:
//   group = chunk>>4 and 2c2 is even so 2c2 mod 16 != 15.
__global__ __launch_bounds__(256) void prep(const float* __restrict__ X,
                                            _Float16* __restrict__ XH,
                                            const int* __restrict__ Q,
                                            const float* __restrict__ S,
                                            _Float16* __restrict__ WH) {
  const int bid = blockIdx.x;
  if (bid < 8192) {
    const size_t i = ((size_t)bid * 256 + threadIdx.x) * 8;
    f32x4 v0 = *(const f32x4*)(X + i);
    f32x4 v1 = *(const f32x4*)(X + i + 4);
    union { fp16x2 h2[4]; half8 h8; } u;
    u.h2[0] = __builtin_amdgcn_cvt_pkrtz(v0.x, v0.y);
    u.h2[1] = __builtin_amdgcn_cvt_pkrtz(v0.z, v0.w);
    u.h2[2] = __builtin_amdgcn_cvt_pkrtz(v1.x, v1.y);
    u.h2[3] = __builtin_amdgcn_cvt_pkrtz(v1.z, v1.w);
    *(half8*)(XH + i) = u.h8;
  } else {
    const int idx = (bid - 8192) * 256 + threadIdx.x;  // [0, 12288*256)
    const int o  = idx >> 8;    // output row (O); 256 int2 per row
    const int c2 = idx & 255;   // int2 index; covers chunks 2c2, 2c2+1
    const int2 q2 = *(const int2*)(Q + (size_t)o * (K_DIM / 8) + c2 * 2);
    const float s = S[o * (K_DIM / 128) + (c2 >> 3)];
    const _Float16 sh = (_Float16)s;
    _Float16* dst = WH + (size_t)o * K_DIM + c2 * 16;
    *(half8*)(dst)     = dequant8((uint32_t)q2.x, sh);
    *(half8*)(dst + 8) = dequant8((uint32_t)q2.y, sh);
  }
}

// f32->f16 only (fallback path)
__global__ __launch_bounds__(256) void cvt_f32_f16(const float* __restrict__ X,
                                                   _Float16* __restrict__ XH) {
  const size_t i = ((size_t)blockIdx.x * 256 + threadIdx.x) * 8;
  f32x4 v0 = *(const f32x4*)(X + i);
  f32x4 v1 = *(const f32x4*)(X + i + 4);
  union { fp16x2 h2[4]; half8 h8; } u;
  u.h2[0] = __builtin_amdgcn_cvt_pkrtz(v0.x, v0.y);
  u.h2[1] = __builtin_amdgcn_cvt_pkrtz(v0.z, v0.w);
  u.h2[2] = __builtin_amdgcn_cvt_pkrtz(v1.x, v1.y);
  u.h2[3] = __builtin_amdgcn_cvt_pkrtz(v1.z, v1.w);
  *(half8*)(XH + i) = u.h8;
}

// ===================== 256x256 8-phase GEMM (T2+T3+T4+T5) =====================
// 512 threads = 8 waves (2M x 4N), per-wave output 128x64.
// Core: mfma_f32_16x16x32_f16 (R6 falsified 32x32: 4-way bank conflict,
// structural — 32-row read groups vs 3-bit XOR swizzle).
//
// R8 = VERIFIED BEST (reproduced R10 within noise). Hoisted reads for
// P2/P3/P6/P7 issue inside the PREVIOUS phase's post-lgkm region, AFTER its
// MFMA burst. R9 falsified both (a) reads-before-burst and (b) P3+P4/P7+P8
// phase merge: at __launch_bounds__(512,2) the unified reg file is 256/wave
// (acc=128 AGPR + ~128 VGPR, exactly at the brim); R9's longer live ranges
// spilled to scratch (WRITE_SIZE 214->286 MB, MfmaUtil 48.5->36).
// At a hard register ceiling, schedule stretch = spill.
//
// Hoist hazards (all SAFE):
//   - P2's bh (buf0 Bs-hi): writer = P3/P4 stage. Read completes at P2's
//     lgkmcnt(0), which every wave passes BEFORE any wave reaches P3's stage
//     (P2 end-barrier orders it).
//   - P3's A-hi (buf0): writer = P5/P6 stage (further).
//   - P6/P7: mirror on buf1 (writers P7/P8 and next-P1/P2).
//   - P1/P5 reads CANNOT hoist: their buffer is published only by the
//     immediately preceding vmcnt(4)+barrier.
// Second A-frag set a2 resolves a-lo (used P2) vs a-hi (loading in P2's
// region) overlap. Lifetimes: a P1->P2, a2 P2->P4, bl P1->P4, bh P1->P3.
//
// LDS: double-buffered A/B K-tiles (BK=64) = 128 KiB (-> 1 block/CU; no
// third buffer possible in 160 KiB).
// READ-COMPLETION LEDGER (last ds_read of each region, post-hoist):
//   buf0 As: P2-region (hoisted a2)   buf0 Bs: P1-region (hoisted bh)
//   buf1 As: P6-region (hoisted a2)   buf1 Bs: P5-region (hoisted bh)
// Stage slots (each >=1 barrier after last read of its target):
//   P1/P2: A(odd)->buf1   P3/P4: B(next even)->buf0
//   P5/P6: A(next even)->buf0   P7/P8: B(next odd)->buf1
// vmcnt ledger (2 loads per stage, per wave): vmcnt(4) at P4 (odd tile
// complete before P5 reads buf1) and P8 (even tile complete before next P1
// reads buf0). vmcnt is PER-WAVE: publication = {all waves' wait} + barrier.
// lgkm policy: explicit lgkmcnt(0)+sched_barrier(0) after each phase barrier
// (R5 falsified removal: +21 us; R7 falsified pre-barrier lgkmcnt(8): +20 us).
// Swizzle: LDS chunk index XOR (row&7); inverse on the global SOURCE address.
// Locality: m-fastest block order (FETCH 841->447 MB, R4); plain C stores
// (nt-stores bypassed L2 write-merge: +26 MB WRITE, slower, R4).

#define WAIT_LGKM0()                                                          \
  do { asm volatile("s_waitcnt lgkmcnt(0)" ::: "memory");                     \
       __builtin_amdgcn_sched_barrier(0); } while (0)
#define WAIT_VM4()                                                            \
  do { asm volatile("s_waitcnt vmcnt(4)" ::: "memory");                       \
       __builtin_amdgcn_sched_barrier(0); } while (0)
#define BARX() __builtin_amdgcn_s_barrier()

#define LDA4(dst, buf, mib)                                                   \
  _Pragma("unroll") for (int j = 0; j < 4; ++j) {                             \
    const int row_ = wm + ((mib) + j) * 16 + rrow;                            \
    dst[j][0] = As[buf][row_ * 8 + (quad ^ (row_ & 7))];                      \
    dst[j][1] = As[buf][row_ * 8 + ((quad + 4) ^ (row_ & 7))];                \
  }

#define LDB2(bb, buf, nib)                                                    \
  _Pragma("unroll") for (int j = 0; j < 2; ++j) {                             \
    const int row_ = wn + ((nib) + j) * 16 + rrow;                            \
    bb[j][0] = Bs[buf][row_ * 8 + (quad ^ (row_ & 7))];                       \
    bb[j][1] = Bs[buf][row_ * 8 + ((quad + 4) ^ (row_ & 7))];                 \
  }

#define MFMAQ(aa, mb, nb, bb)                                                 \
  do {                                                                        \
    __builtin_amdgcn_s_setprio(1);                                            \
    _Pragma("unroll") for (int mi = 0; mi < 4; ++mi)                          \
      _Pragma("unroll") for (int ni = 0; ni < 2; ++ni)                        \
        _Pragma("unroll") for (int kk = 0; kk < 2; ++kk)                      \
          acc[(mb) + mi][(nb) + ni] = __builtin_amdgcn_mfma_f32_16x16x32_f16( \
              aa[mi][kk], bb[ni][kk], acc[(mb) + mi][(nb) + ni], 0, 0, 0);    \
    __builtin_amdgcn_s_setprio(0);                                            \
  } while (0)

#define STAGE_A(buf, h, koff)                                                 \
  do {                                                                        \
    GLOAD_LDS16(XH + aOff[h][0] + (koff), &As[buf][(h)*1024 + wave * 64]);    \
    GLOAD_LDS16(XH + aOff[h][1] + (koff), &As[buf][(h)*1024 + 512 + wave*64]);\
  } while (0)
#define STAGE_B(buf, h, koff)                                                 \
  do {                                                                        \
    GLOAD_LDS16(WH + bOff[h][0] + (koff), &Bs[buf][(h)*1024 + wave * 64]);    \
    GLOAD_LDS16(WH + bOff[h][1] + (koff), &Bs[buf][(h)*1024 + 512 + wave*64]);\
  } while (0)

__global__ __launch_bounds__(512, 2) void gemm_f16_8p(
    const _Float16* __restrict__ XH, const _Float16* __restrict__ WH,
    const float* __restrict__ Bias, float* __restrict__ C) {
  __shared__ half8 As[2][2048];   // [buf][row*8 + swz-chunk], 256 rows x 64 k
  __shared__ half8 Bs[2][2048];

  const int tid  = threadIdx.x;
  const int lane = tid & 63;
  const int wave = tid >> 6;
  const int wm   = (wave >> 2) * 128;  // wave M origin within tile
  const int wn   = (wave & 3) * 64;    // wave N origin within tile
  const int rrow = lane & 15;
  const int quad = lane >> 4;

  // XCD-aware bijective swizzle: 768 blocks, 768 % 8 == 0.
  // m-FASTEST order: concurrent blocks cover all 16 m-tiles (A L3-resident)
  // and cluster the 16 readers of each W n-panel close in time.
  const int bid = blockIdx.x;
  const int swz = (bid & 7) * 96 + (bid >> 3);
  const int m0  = (swz & 15) * 256;   // 16 m-tiles, fastest
  const int n0  = (swz >> 4) * 256;   // 48 n-tiles

  // Per-lane inverse-swizzled global source offsets (elements).
  // LDS slot s = r*512 + tid within a 128-row half; row = s>>3,
  // global chunk c = (s&7) ^ (row&7).
  uint32_t aOff[2][2], bOff[2][2];
  #pragma unroll
  for (int h = 0; h < 2; ++h)
    #pragma unroll
    for (int r = 0; r < 2; ++r) {
      const int slot = r * 512 + tid;
      const int row  = slot >> 3;
      const int c    = (slot & 7) ^ (row & 7);
      aOff[h][r] = (uint32_t)((m0 + h * 128 + row) * K_DIM + c * 8);
      bOff[h][r] = (uint32_t)((n0 + h * 128 + row) * K_DIM + c * 8);
    }

  f32x4 acc[8][4];
  #pragma unroll
  for (int i = 0; i < 8; ++i)
    #pragma unroll
    for (int j = 0; j < 4; ++j)
      acc[i][j] = (f32x4){0.f, 0.f, 0.f, 0.f};

  half8 a[4][2], a2[4][2], bl[2][2], bh[2][2];

  // Prologue ("iteration -1" P3..P8): tile0 fully -> buf0 (8 loads, oldest),
  // then tile1 B -> buf1 (4 loads). vmcnt(4) -> tile0's 8 landed.
  STAGE_B(0, 0, 0);  STAGE_B(0, 1, 0);  STAGE_A(0, 0, 0);  STAGE_A(0, 1, 0);
  STAGE_B(1, 0, 64); STAGE_B(1, 1, 64);
  WAIT_VM4();
  BARX();

  // 32 iterations x 2 K-tiles (NT = 64).
  for (int it = 0; it < 32; ++it) {
    const int k1  = it * 128 + 64;                  // current odd tile
    const int kp0 = (it < 31) ? it * 128 + 128 : 0; // prefetch tile 2it+2
    const int kp1 = (it < 31) ? it * 128 + 192 : 0; // prefetch tile 2it+3

    // P1: (Mlo,Nlo) of buf0; stage A-h0(current odd) -> buf1.
    // Post-MFMA: hoist P2's bh reads (interleave with MFMA issue).
    LDA4(a, 0, 0);
    LDB2(bl, 0, 0);
    STAGE_A(1, 0, k1);
    BARX(); WAIT_LGKM0();
    MFMAQ(a, 0, 0, bl);
    LDB2(bh, 0, 2);
    BARX();

    // P2: (Mlo,Nhi); stage A-h1(current odd) -> buf1.
    // Post-MFMA: hoist P3/P4's A-hi reads into a2.
    STAGE_A(1, 1, k1);
    BARX(); WAIT_LGKM0();
    MFMAQ(a, 0, 2, bh);
    LDA4(a2, 0, 4);
    BARX();

    // P3: (Mhi,Nhi) from a2; stage B-h0(next even) -> buf0 [buf0 Bs read-done P1]
    STAGE_B(0, 0, kp0);
    BARX(); WAIT_LGKM0();
    MFMAQ(a2, 4, 2, bh);
    BARX();

    // P4: (Mhi,Nlo) from regs; stage B-h1(next even) -> buf0; vmcnt(4)
    // -> odd tile (prev P7/P8 B + P1/P2 A) fully landed before P5 reads.
    STAGE_B(0, 1, kp0);
    BARX();
    MFMAQ(a2, 4, 0, bl);
    WAIT_VM4();
    BARX();

    // P5: (Mlo,Nlo) of buf1; stage A-h0(next even) -> buf0 [buf0 As read-done P2]
    // Post-MFMA: hoist P6's bh reads.
    LDA4(a, 1, 0);
    LDB2(bl, 1, 0);
    STAGE_A(0, 0, kp0);
    BARX(); WAIT_LGKM0();
    MFMAQ(a, 0, 0, bl);
    LDB2(bh, 1, 2);
    BARX();

    // P6: (Mlo,Nhi); stage A-h1(next even) -> buf0.
    // Post-MFMA: hoist P7/P8's A-hi reads into a2.
    STAGE_A(0, 1, kp0);
    BARX(); WAIT_LGKM0();
    MFMAQ(a, 0, 2, bh);
    LDA4(a2, 1, 4);
    BARX();

    // P7: (Mhi,Nhi) from a2; stage B-h0(next odd) -> buf1 [buf1 Bs read-done P5]
    STAGE_B(1, 0, kp1);
    BARX(); WAIT_LGKM0();
    MFMAQ(a2, 4, 2, bh);
    BARX();

    // P8: (Mhi,Nlo) from regs; stage B-h1(next odd) -> buf1; vmcnt(4)
    // -> next even tile (P3..P6 stages, buf0) landed before next P1 reads.
    STAGE_B(1, 1, kp1);
    BARX();
    MFMAQ(a2, 4, 0, bl);
    WAIT_VM4();
    BARX();
  }

  // Epilogue: C/D layout col(n)=lane&15, row(m)=quad*4+reg [m89].
  // Plain stores (nt-stores: +26 MB WRITE_SIZE, slower — R4). WRITE_SIZE
  // 216 MB vs 201 ideal -> writes already ~93% efficient, no transpose needed.
  #pragma unroll
  for (int ni = 0; ni < 4; ++ni) {
    const int n = n0 + wn + ni * 16 + rrow;
    const float bv = Bias[n];
    #pragma unroll
    for (int mi = 0; mi < 8; ++mi) {
      const int mbase = m0 + wm + mi * 16 + quad * 4;
      #pragma unroll
      for (int rr = 0; rr < 4; ++rr) {
        C[(size_t)(mbase + rr) * N_DIM + n] = acc[mi][ni][rr] + bv;
      }
    }
  }
}

// ---------------- fallback (previous verified 128^2 kernel) ----------------
template <bool PRE>
__global__ __launch_bounds__(256) void awq_gemm(
    const float* __restrict__ X, const _Float16* __restrict__ XH,
    const int* __restrict__ Q, const float* __restrict__ S,
    const float* __restrict__ Bias, float* __restrict__ C) {
  __shared__ half8 Asf[BM * 8];
  __shared__ half8 Bsf[BN * 8];

  const int tid  = threadIdx.x;
  const int lane = tid & 63;
  const int wave = tid >> 6;
  const int wm   = (wave >> 1) * 64;
  const int wn   = (wave & 1) * 64;
  const int m0   = blockIdx.y * BM;
  const int n0   = blockIdx.x * BN;
  const int rrow = lane & 15;
  const int quad = lane >> 4;

  const _Float16* a_gp[4];
  if (PRE) {
    #pragma unroll
    for (int r = 0; r < 4; ++r) {
      const int slot = (wave * 4 + r) * 64 + lane;
      const int row  = slot >> 3;
      const int c    = (slot & 7) ^ (row & 7);
      a_gp[r] = XH + (size_t)(m0 + row) * K_DIM + c * 8;
    }
  }

  int brow[4], bcol[4];
  #pragma unroll
  for (int r = 0; r < 4; ++r) {
    const int idx = tid + 256 * r;
    brow[r] = idx >> 3;
    bcol[r] = idx & 7;
  }

  f32x4 acc[4][4];
  #pragma unroll
  for (int i = 0; i < 4; ++i)
    #pragma unroll
    for (int j = 0; j < 4; ++j)
      acc[i][j] = (f32x4){0.f, 0.f, 0.f, 0.f};

  for (int k0 = 0; k0 < K_DIM; k0 += BK) {
    if (PRE) {
      #pragma unroll
      for (int r = 0; r < 4; ++r)
        GLOAD_LDS16(a_gp[r] + k0, &Asf[(wave * 4 + r) * 64]);
    } else {
      #pragma unroll
      for (int r = 0; r < 4; ++r) {
        const int ch  = tid + 256 * r;
        const int row = ch >> 3;
        const int c   = ch & 7;
        const float* p = X + (size_t)(m0 + row) * K_DIM + k0 + c * 8;
        f32x4 v0 = *(const f32x4*)p;
        f32x4 v1 = *(const f32x4*)(p + 4);
        union { fp16x2 h2[4]; half8 h8; } u;
        u.h2[0] = __builtin_amdgcn_cvt_pkrtz(v0.x, v0.y);
        u.h2[1] = __builtin_amdgcn_cvt_pkrtz(v0.z, v0.w);
        u.h2[2] = __builtin_amdgcn_cvt_pkrtz(v1.x, v1.y);
        u.h2[3] = __builtin_amdgcn_cvt_pkrtz(v1.z, v1.w);
        Asf[row * 8 + (c ^ (row & 7))] = u.h8;
      }
    }
    #pragma unroll
    for (int r = 0; r < 4; ++r) {
      const int row = brow[r];
      const int c   = bcol[r];
      const uint32_t q =
          (uint32_t)Q[(size_t)(n0 + row) * (K_DIM / 8) + (k0 >> 3) + c];
      const float s = S[(size_t)(n0 + row) * (K_DIM / 128) + (k0 >> 7)];
      Bsf[row * 8 + (c ^ (row & 7))] = dequant8(q, (_Float16)s);
    }
    __syncthreads();

    #pragma unroll
    for (int kk = 0; kk < 2; ++kk) {
      const int kch = kk * 4 + quad;
      half8 a[4], b[4];
      #pragma unroll
      for (int mi = 0; mi < 4; ++mi) {
        const int row = wm + mi * 16 + rrow;
        a[mi] = Asf[row * 8 + (kch ^ (row & 7))];
      }
      #pragma unroll
      for (int ni = 0; ni < 4; ++ni) {
        const int row = wn + ni * 16 + rrow;
        b[ni] = Bsf[row * 8 + (kch ^ (row & 7))];
      }
      #pragma unroll
      for (int mi = 0; mi < 4; ++mi)
        #pragma unroll
        for (int ni = 0; ni < 4; ++ni)
          acc[mi][ni] = __builtin_amdgcn_mfma_f32_16x16x32_f16(
              a[mi], b[ni], acc[mi][ni], 0, 0, 0);
    }
    __syncthreads();
  }

  #pragma unroll
  for (int ni = 0; ni < 4; ++ni) {
    const int n = n0 + wn + ni * 16 + rrow;
    const float bv = Bias[n];
    #pragma unroll
    for (int mi = 0; mi < 4; ++mi) {
      const int mbase = m0 + wm + mi * 16 + quad * 4;
      #pragma unroll
      for (int rr = 0; rr < 4; ++rr) {
        C[(size_t)(mbase + rr) * N_DIM + n] = acc[mi][ni][rr] + bv;
      }
    }
  }
}

extern "C" void kernel_launch(void* const* d_in, const int* in_sizes, int n_in,
                              void* d_out, int out_size, void* d_ws, size_t ws_size,
                              hipStream_t stream) {
  const float* X    = (const float*)d_in[0];
  const int*   Q    = (const int*)d_in[1];
  const float* S    = (const float*)d_in[2];
  const float* Bias = (const float*)d_in[3];
  float* C = (float*)d_out;

  const size_t needXH = (size_t)M_DIM * K_DIM * sizeof(_Float16);  // 32 MiB
  const size_t needWH = (size_t)N_DIM * K_DIM * sizeof(_Float16);  // 96 MiB
  if (ws_size >= needXH + needWH) {
    _Float16* XH = (_Float16*)d_ws;
    _Float16* WH = (_Float16*)((char*)d_ws + needXH);
    // 8192 X-blocks + 12288 W-blocks (int2-vectorized dequant)
    prep<<<dim3(8192 + 12288), dim3(256), 0, stream>>>(X, XH, Q, S, WH);
    gemm_f16_8p<<<dim3(768), dim3(512), 0, stream>>>(XH, WH, Bias, C);
  } else if (ws_size >= needXH) {
    _Float16* XH = (_Float16*)d_ws;
    cvt_f32_f16<<<(M_DIM * (size_t)K_DIM) / 8 / 256, 256, 0, stream>>>(X, XH);
    awq_gemm<true><<<dim3(N_DIM / BN, M_DIM / BM), dim3(256), 0, stream>>>(
        X, XH, Q, S, Bias, C);
  } else {
    awq_gemm<false><<<dim3(N_DIM / BN, M_DIM / BM), dim3(256), 0, stream>>>(
        X, nullptr, Q, S, Bias, C);
  }
}

// Round 12
// 610.855 us; speedup vs baseline: 1.1552x; 1.0157x over previous
//
#include <hip/hip_runtime.h>
#include <stdint.h>

#define M_DIM 4096
#define K_DIM 4096
#define N_DIM 12288

// fallback tile (old verified 128^2 kernel)
#define BM 128
#define BN 128
#define BK 64

typedef __attribute__((ext_vector_type(8))) _Float16 half8;
typedef __attribute__((ext_vector_type(2))) __fp16 fp16x2;
typedef __attribute__((ext_vector_type(4))) float f32x4;

#define GLOAD_LDS16(gp, lp)                                                   \
  __builtin_amdgcn_global_load_lds(                                           \
      (const __attribute__((address_space(1))) void*)(gp),                    \
      (__attribute__((address_space(3))) void*)(lp), 16, 0, 0)

// 8 nibbles (high-first) -> 8 f16 weights, single-rounded:
// h = 1024 + n exactly (0x6400|n); (h - 1024) is exact; one mul rounds.
static __device__ __forceinline__ half8 dequant8(uint32_t q, _Float16 sh) {
  union { uint32_t u[4]; half8 h; } w;
  w.u[0] = 0x64006400u | ((q >> 28) & 0xFu) | ((q >> 8)  & 0xF0000u);
  w.u[1] = 0x64006400u | ((q >> 20) & 0xFu) | ( q         & 0xF0000u);
  w.u[2] = 0x64006400u | ((q >> 12) & 0xFu) | ((q << 8)  & 0xF0000u);
  w.u[3] = 0x64006400u | ((q >> 4)  & 0xFu) | ((q << 16) & 0xF0000u);
  half8 hv = w.h;
  half8 mm, ss;
  #pragma unroll
  for (int i = 0; i < 8; ++i) { mm[i] = (_Float16)(-1024.0f); ss[i] = sh; }
  return (hv + mm) * ss;   // pk_add_f16 + pk_mul_f16, vectorized
}

// Merged prep (R11: W-part vectorized per G13):
//   blocks [0,8192): convert X f32->f16, 8 floats/thread.
//   blocks [8192,20480): dequant W, int2 Q load (8 B) -> 2 chunks -> 32 B
//   of f16 per thread. Chunk pair (2c2, 2c2+1) always shares a scale group:
//   group = chunk>>4 and 2c2 is even so 2c2 mod 16 != 15.
__global__ __launch_bounds__(256) void prep(const float* __restrict__ X,
                                            _Float16* __restrict__ XH,
                                            const int* __restrict__ Q,
                                            const float* __restrict__ S,
                                            _Float16* __restrict__ WH) {
  const int bid = blockIdx.x;
  if (bid < 8192) {
    const size_t i = ((size_t)bid * 256 + threadIdx.x) * 8;
    f32x4 v0 = *(const f32x4*)(X + i);
    f32x4 v1 = *(const f32x4*)(X + i + 4);
    union { fp16x2 h2[4]; half8 h8; } u;
    u.h2[0] = __builtin_amdgcn_cvt_pkrtz(v0.x, v0.y);
    u.h2[1] = __builtin_amdgcn_cvt_pkrtz(v0.z, v0.w);
    u.h2[2] = __builtin_amdgcn_cvt_pkrtz(v1.x, v1.y);
    u.h2[3] = __builtin_amdgcn_cvt_pkrtz(v1.z, v1.w);
    *(half8*)(XH + i) = u.h8;
  } else {
    const int idx = (bid - 8192) * 256 + threadIdx.x;  // [0, 12288*256)
    const int o  = idx >> 8;    // output row (O); 256 int2 per row
    const int c2 = idx & 255;   // int2 index; covers chunks 2c2, 2c2+1
    const int2 q2 = *(const int2*)(Q + (size_t)o * (K_DIM / 8) + c2 * 2);
    const float s = S[o * (K_DIM / 128) + (c2 >> 3)];
    const _Float16 sh = (_Float16)s;
    _Float16* dst = WH + (size_t)o * K_DIM + c2 * 16;
    *(half8*)(dst)     = dequant8((uint32_t)q2.x, sh);
    *(half8*)(dst + 8) = dequant8((uint32_t)q2.y, sh);
  }
}

// f32->f16 only (fallback path)
__global__ __launch_bounds__(256) void cvt_f32_f16(const float* __restrict__ X,
                                                   _Float16* __restrict__ XH) {
  const size_t i = ((size_t)blockIdx.x * 256 + threadIdx.x) * 8;
  f32x4 v0 = *(const f32x4*)(X + i);
  f32x4 v1 = *(const f32x4*)(X + i + 4);
  union { fp16x2 h2[4]; half8 h8; } u;
  u.h2[0] = __builtin_amdgcn_cvt_pkrtz(v0.x, v0.y);
  u.h2[1] = __builtin_amdgcn_cvt_pkrtz(v0.z, v0.w);
  u.h2[2] = __builtin_amdgcn_cvt_pkrtz(v1.x, v1.y);
  u.h2[3] = __builtin_amdgcn_cvt_pkrtz(v1.z, v1.w);
  *(half8*)(XH + i) = u.h8;
}

// ===================== 256x256 8-phase GEMM (T2+T3+T4+T5) =====================
// 512 threads = 8 waves (2M x 4N), per-wave output 128x64.
// Core: mfma_f32_16x16x32_f16 (R6 falsified 32x32: 4-way bank conflict,
// structural — 32-row read groups vs 3-bit XOR swizzle).
//
// R12: SINGLE BARRIER PER PHASE. Pipe arithmetic per CU per K-tile:
// MFMA 512x4.85=2483 cyc, LDS 192x12=2304 cyc — near-equal, so the old
// mid-phase barrier (between read-burst and MFMA-burst) enforced block-level
// mutual exclusion of the two pipes (MfmaUtil stuck ~47%). Ledger proof the
// mid-phase barrier is removable (WAR margins stay >=1 END barrier):
//   buf0 Bs last-read (P1 hoisted bh) vs P3 stage: P1-end,P2-end = 2 barriers
//   buf0 As last-read (P2 hoisted a2) vs P5 stage: P2/P3/P4 ends = 3
//   buf1 As last-read (P6 hoisted a2) vs next-P1 stage: P6/P7/P8 ends = 3
//   buf1 Bs last-read (P5 hoisted bh) vs P7 stage: P5/P6 ends = 2
// RAW publication unchanged: {all waves vmcnt(4)} + P4/P8 END barrier.
// Slipped-wave check: a wave reaches phase N+2's stage only after passing
// N and N+1 end-barriers, which every other wave's phase-N reads precede
// (their lgkm0 is before their end-barrier). No new live registers (R9's
// spill failure mode does not apply). 16 -> 8 barriers/iteration; waves can
// slip so one wave's MFMA burst covers another's read burst.
//
// R8-hoist retained: P2/P3/P6/P7's reads issue in the PREVIOUS phase's
// post-lgkm region, after its MFMA burst. P1/P5 reads cannot hoist (their
// buffer publishes at the immediately preceding vmcnt+barrier).
// Second A-frag set a2: lifetimes a P1->P2, a2 P2->P4, bl P1->P4, bh P1->P3.
// Register budget: __launch_bounds__(512,2) -> 256/wave; acc=128 + frags 96
// + addressing ~= at the brim; schedule stretch = spill (R9).
//
// LDS: double-buffered A/B K-tiles (BK=64) = 128 KiB (1 block/CU).
// vmcnt ledger (2 loads per stage, per wave): vmcnt(4) at P4 (odd tile
// complete before P5 reads buf1) and P8 (even tile complete before next P1
// reads buf0). vmcnt is PER-WAVE: publication = {all waves' wait} + barrier.
// lgkm policy: explicit lgkmcnt(0)+sched_barrier(0) before each MFMA burst
// (R5 falsified removal: +21 us; R7 falsified pre-barrier lgkmcnt(8): +20 us).
// Swizzle: LDS chunk index XOR (row&7); inverse on the global SOURCE address.
// Locality: m-fastest block order (FETCH 841->447 MB, R4); plain C stores
// (nt-stores bypassed L2 write-merge: +26 MB WRITE, slower, R4).

#define WAIT_LGKM0()                                                          \
  do { asm volatile("s_waitcnt lgkmcnt(0)" ::: "memory");                     \
       __builtin_amdgcn_sched_barrier(0); } while (0)
#define WAIT_VM4()                                                            \
  do { asm volatile("s_waitcnt vmcnt(4)" ::: "memory");                       \
       __builtin_amdgcn_sched_barrier(0); } while (0)
#define BARX() __builtin_amdgcn_s_barrier()

#define LDA4(dst, buf, mib)                                                   \
  _Pragma("unroll") for (int j = 0; j < 4; ++j) {                             \
    const int row_ = wm + ((mib) + j) * 16 + rrow;                            \
    dst[j][0] = As[buf][row_ * 8 + (quad ^ (row_ & 7))];                      \
    dst[j][1] = As[buf][row_ * 8 + ((quad + 4) ^ (row_ & 7))];                \
  }

#define LDB2(bb, buf, nib)                                                    \
  _Pragma("unroll") for (int j = 0; j < 2; ++j) {                             \
    const int row_ = wn + ((nib) + j) * 16 + rrow;                            \
    bb[j][0] = Bs[buf][row_ * 8 + (quad ^ (row_ & 7))];                       \
    bb[j][1] = Bs[buf][row_ * 8 + ((quad + 4) ^ (row_ & 7))];                 \
  }

#define MFMAQ(aa, mb, nb, bb)                                                 \
  do {                                                                        \
    __builtin_amdgcn_s_setprio(1);                                            \
    _Pragma("unroll") for (int mi = 0; mi < 4; ++mi)                          \
      _Pragma("unroll") for (int ni = 0; ni < 2; ++ni)                        \
        _Pragma("unroll") for (int kk = 0; kk < 2; ++kk)                      \
          acc[(mb) + mi][(nb) + ni] = __builtin_amdgcn_mfma_f32_16x16x32_f16( \
              aa[mi][kk], bb[ni][kk], acc[(mb) + mi][(nb) + ni], 0, 0, 0);    \
    __builtin_amdgcn_s_setprio(0);                                            \
  } while (0)

#define STAGE_A(buf, h, koff)                                                 \
  do {                                                                        \
    GLOAD_LDS16(XH + aOff[h][0] + (koff), &As[buf][(h)*1024 + wave * 64]);    \
    GLOAD_LDS16(XH + aOff[h][1] + (koff), &As[buf][(h)*1024 + 512 + wave*64]);\
  } while (0)
#define STAGE_B(buf, h, koff)                                                 \
  do {                                                                        \
    GLOAD_LDS16(WH + bOff[h][0] + (koff), &Bs[buf][(h)*1024 + wave * 64]);    \
    GLOAD_LDS16(WH + bOff[h][1] + (koff), &Bs[buf][(h)*1024 + 512 + wave*64]);\
  } while (0)

__global__ __launch_bounds__(512, 2) void gemm_f16_8p(
    const _Float16* __restrict__ XH, const _Float16* __restrict__ WH,
    const float* __restrict__ Bias, float* __restrict__ C) {
  __shared__ half8 As[2][2048];   // [buf][row*8 + swz-chunk], 256 rows x 64 k
  __shared__ half8 Bs[2][2048];

  const int tid  = threadIdx.x;
  const int lane = tid & 63;
  const int wave = tid >> 6;
  const int wm   = (wave >> 2) * 128;  // wave M origin within tile
  const int wn   = (wave & 3) * 64;    // wave N origin within tile
  const int rrow = lane & 15;
  const int quad = lane >> 4;

  // XCD-aware bijective swizzle: 768 blocks, 768 % 8 == 0.
  // m-FASTEST order: concurrent blocks cover all 16 m-tiles (A L3-resident)
  // and cluster the 16 readers of each W n-panel close in time.
  const int bid = blockIdx.x;
  const int swz = (bid & 7) * 96 + (bid >> 3);
  const int m0  = (swz & 15) * 256;   // 16 m-tiles, fastest
  const int n0  = (swz >> 4) * 256;   // 48 n-tiles

  // Per-lane inverse-swizzled global source offsets (elements).
  // LDS slot s = r*512 + tid within a 128-row half; row = s>>3,
  // global chunk c = (s&7) ^ (row&7).
  uint32_t aOff[2][2], bOff[2][2];
  #pragma unroll
  for (int h = 0; h < 2; ++h)
    #pragma unroll
    for (int r = 0; r < 2; ++r) {
      const int slot = r * 512 + tid;
      const int row  = slot >> 3;
      const int c    = (slot & 7) ^ (row & 7);
      aOff[h][r] = (uint32_t)((m0 + h * 128 + row) * K_DIM + c * 8);
      bOff[h][r] = (uint32_t)((n0 + h * 128 + row) * K_DIM + c * 8);
    }

  f32x4 acc[8][4];
  #pragma unroll
  for (int i = 0; i < 8; ++i)
    #pragma unroll
    for (int j = 0; j < 4; ++j)
      acc[i][j] = (f32x4){0.f, 0.f, 0.f, 0.f};

  half8 a[4][2], a2[4][2], bl[2][2], bh[2][2];

  // Prologue ("iteration -1" P3..P8): tile0 fully -> buf0 (8 loads, oldest),
  // then tile1 B -> buf1 (4 loads). vmcnt(4) -> tile0's 8 landed.
  STAGE_B(0, 0, 0);  STAGE_B(0, 1, 0);  STAGE_A(0, 0, 0);  STAGE_A(0, 1, 0);
  STAGE_B(1, 0, 64); STAGE_B(1, 1, 64);
  WAIT_VM4();
  BARX();

  // 32 iterations x 2 K-tiles (NT = 64). ONE barrier per phase (at its end).
  for (int it = 0; it < 32; ++it) {
    const int k1  = it * 128 + 64;                  // current odd tile
    const int kp0 = (it < 31) ? it * 128 + 128 : 0; // prefetch tile 2it+2
    const int kp1 = (it < 31) ? it * 128 + 192 : 0; // prefetch tile 2it+3

    // P1: (Mlo,Nlo) of buf0; stage A-h0(current odd) -> buf1.
    // Post-MFMA: hoist P2's bh reads.
    LDA4(a, 0, 0);
    LDB2(bl, 0, 0);
    STAGE_A(1, 0, k1);
    WAIT_LGKM0();
    MFMAQ(a, 0, 0, bl);
    LDB2(bh, 0, 2);
    BARX();

    // P2: (Mlo,Nhi); stage A-h1(current odd) -> buf1.
    // Post-MFMA: hoist P3/P4's A-hi reads into a2.
    STAGE_A(1, 1, k1);
    WAIT_LGKM0();
    MFMAQ(a, 0, 2, bh);
    LDA4(a2, 0, 4);
    BARX();

    // P3: (Mhi,Nhi) from a2; stage B-h0(next even) -> buf0
    // [buf0 Bs read-done P1; P1-end,P2-end barriers between]
    STAGE_B(0, 0, kp0);
    WAIT_LGKM0();
    MFMAQ(a2, 4, 2, bh);
    BARX();

    // P4: (Mhi,Nlo) from regs; stage B-h1(next even) -> buf0; vmcnt(4)
    // -> odd tile (prev P7/P8 B + P1/P2 A) fully landed before P5 reads.
    STAGE_B(0, 1, kp0);
    MFMAQ(a2, 4, 0, bl);
    WAIT_VM4();
    BARX();

    // P5: (Mlo,Nlo) of buf1; stage A-h0(next even) -> buf0
    // [buf0 As read-done P2; P2/P3/P4 end barriers between]
    LDA4(a, 1, 0);
    LDB2(bl, 1, 0);
    STAGE_A(0, 0, kp0);
    WAIT_LGKM0();
    MFMAQ(a, 0, 0, bl);
    LDB2(bh, 1, 2);
    BARX();

    // P6: (Mlo,Nhi); stage A-h1(next even) -> buf0.
    STAGE_A(0, 1, kp0);
    WAIT_LGKM0();
    MFMAQ(a, 0, 2, bh);
    LDA4(a2, 1, 4);
    BARX();

    // P7: (Mhi,Nhi) from a2; stage B-h0(next odd) -> buf1
    // [buf1 Bs read-done P5; P5/P6 end barriers between]
    STAGE_B(1, 0, kp1);
    WAIT_LGKM0();
    MFMAQ(a2, 4, 2, bh);
    BARX();

    // P8: (Mhi,Nlo) from regs; stage B-h1(next odd) -> buf1; vmcnt(4)
    // -> next even tile (P3..P6 stages, buf0) landed before next P1 reads.
    STAGE_B(1, 1, kp1);
    MFMAQ(a2, 4, 0, bl);
    WAIT_VM4();
    BARX();
  }

  // Epilogue: C/D layout col(n)=lane&15, row(m)=quad*4+reg [m89].
  // Plain stores (nt-stores: +26 MB WRITE_SIZE, slower — R4). WRITE_SIZE
  // 216 MB vs 201 ideal -> writes already ~93% efficient.
  #pragma unroll
  for (int ni = 0; ni < 4; ++ni) {
    const int n = n0 + wn + ni * 16 + rrow;
    const float bv = Bias[n];
    #pragma unroll
    for (int mi = 0; mi < 8; ++mi) {
      const int mbase = m0 + wm + mi * 16 + quad * 4;
      #pragma unroll
      for (int rr = 0; rr < 4; ++rr) {
        C[(size_t)(mbase + rr) * N_DIM + n] = acc[mi][ni][rr] + bv;
      }
    }
  }
}

// ---------------- fallback (previous verified 128^2 kernel) ----------------
template <bool PRE>
__global__ __launch_bounds__(256) void awq_gemm(
    const float* __restrict__ X, const _Float16* __restrict__ XH,
    const int* __restrict__ Q, const float* __restrict__ S,
    const float* __restrict__ Bias, float* __restrict__ C) {
  __shared__ half8 Asf[BM * 8];
  __shared__ half8 Bsf[BN * 8];

  const int tid  = threadIdx.x;
  const int lane = tid & 63;
  const int wave = tid >> 6;
  const int wm   = (wave >> 1) * 64;
  const int wn   = (wave & 1) * 64;
  const int m0   = blockIdx.y * BM;
  const int n0   = blockIdx.x * BN;
  const int rrow = lane & 15;
  const int quad = lane >> 4;

  const _Float16* a_gp[4];
  if (PRE) {
    #pragma unroll
    for (int r = 0; r < 4; ++r) {
      const int slot = (wave * 4 + r) * 64 + lane;
      const int row  = slot >> 3;
      const int c    = (slot & 7) ^ (row & 7);
      a_gp[r] = XH + (size_t)(m0 + row) * K_DIM + c * 8;
    }
  }

  int brow[4], bcol[4];
  #pragma unroll
  for (int r = 0; r < 4; ++r) {
    const int idx = tid + 256 * r;
    brow[r] = idx >> 3;
    bcol[r] = idx & 7;
  }

  f32x4 acc[4][4];
  #pragma unroll
  for (int i = 0; i < 4; ++i)
    #pragma unroll
    for (int j = 0; j < 4; ++j)
      acc[i][j] = (f32x4){0.f, 0.f, 0.f, 0.f};

  for (int k0 = 0; k0 < K_DIM; k0 += BK) {
    if (PRE) {
      #pragma unroll
      for (int r = 0; r < 4; ++r)
        GLOAD_LDS16(a_gp[r] + k0, &Asf[(wave * 4 + r) * 64]);
    } else {
      #pragma unroll
      for (int r = 0; r < 4; ++r) {
        const int ch  = tid + 256 * r;
        const int row = ch >> 3;
        const int c   = ch & 7;
        const float* p = X + (size_t)(m0 + row) * K_DIM + k0 + c * 8;
        f32x4 v0 = *(const f32x4*)p;
        f32x4 v1 = *(const f32x4*)(p + 4);
        union { fp16x2 h2[4]; half8 h8; } u;
        u.h2[0] = __builtin_amdgcn_cvt_pkrtz(v0.x, v0.y);
        u.h2[1] = __builtin_amdgcn_cvt_pkrtz(v0.z, v0.w);
        u.h2[2] = __builtin_amdgcn_cvt_pkrtz(v1.x, v1.y);
        u.h2[3] = __builtin_amdgcn_cvt_pkrtz(v1.z, v1.w);
        Asf[row * 8 + (c ^ (row & 7))] = u.h8;
      }
    }
    #pragma unroll
    for (int r = 0; r < 4; ++r) {
      const int row = brow[r];
      const int c   = bcol[r];
      const uint32_t q =
          (uint32_t)Q[(size_t)(n0 + row) * (K_DIM / 8) + (k0 >> 3) + c];
      const float s = S[(size_t)(n0 + row) * (K_DIM / 128) + (k0 >> 7)];
      Bsf[row * 8 + (c ^ (row & 7))] = dequant8(q, (_Float16)s);
    }
    __syncthreads();

    #pragma unroll
    for (int kk = 0; kk < 2; ++kk) {
      const int kch = kk * 4 + quad;
      half8 a[4], b[4];
      #pragma unroll
      for (int mi = 0; mi < 4; ++mi) {
        const int row = wm + mi * 16 + rrow;
        a[mi] = Asf[row * 8 + (kch ^ (row & 7))];
      }
      #pragma unroll
      for (int ni = 0; ni < 4; ++ni) {
        const int row = wn + ni * 16 + rrow;
        b[ni] = Bsf[row * 8 + (kch ^ (row & 7))];
      }
      #pragma unroll
      for (int mi = 0; mi < 4; ++mi)
        #pragma unroll
        for (int ni = 0; ni < 4; ++ni)
          acc[mi][ni] = __builtin_amdgcn_mfma_f32_16x16x32_f16(
              a[mi], b[ni], acc[mi][ni], 0, 0, 0);
    }
    __syncthreads();
  }

  #pragma unroll
  for (int ni = 0; ni < 4; ++ni) {
    const int n = n0 + wn + ni * 16 + rrow;
    const float bv = Bias[n];
    #pragma unroll
    for (int mi = 0; mi < 4; ++mi) {
      const int mbase = m0 + wm + mi * 16 + quad * 4;
      #pragma unroll
      for (int rr = 0; rr < 4; ++rr) {
        C[(size_t)(mbase + rr) * N_DIM + n] = acc[mi][ni][rr] + bv;
      }
    }
  }
}

extern "C" void kernel_launch(void* const* d_in, const int* in_sizes, int n_in,
                              void* d_out, int out_size, void* d_ws, size_t ws_size,
                              hipStream_t stream) {
  const float* X    = (const float*)d_in[0];
  const int*   Q    = (const int*)d_in[1];
  const float* S    = (const float*)d_in[2];
  const float* Bias = (const float*)d_in[3];
  float* C = (float*)d_out;

  const size_t needXH = (size_t)M_DIM * K_DIM * sizeof(_Float16);  // 32 MiB
  const size_t needWH = (size_t)N_DIM * K_DIM * sizeof(_Float16);  // 96 MiB
  if (ws_size >= needXH + needWH) {
    _Float16* XH = (_Float16*)d_ws;
    _Float16* WH = (_Float16*)((char*)d_ws + needXH);
    // 8192 X-blocks + 12288 W-blocks (int2-vectorized dequant)
    prep<<<dim3(8192 + 12288), dim3(256), 0, stream>>>(X, XH, Q, S, WH);
    gemm_f16_8p<<<dim3(768), dim3(512), 0, stream>>>(XH, WH, Bias, C);
  } else if (ws_size >= needXH) {
    _Float16* XH = (_Float16*)d_ws;
    cvt_f32_f16<<<(M_DIM * (size_t)K_DIM) / 8 / 256, 256, 0, stream>>>(X, XH);
    awq_gemm<true><<<dim3(N_DIM / BN, M_DIM / BM), dim3(256), 0, stream>>>(
        X, XH, Q, S, Bias, C);
  } else {
    awq_gemm<false><<<dim3(N_DIM / BN, M_DIM / BM), dim3(256), 0, stream>>>(
        X, nullptr, Q, S, Bias, C);
  }
}